// Round 9
// baseline (62.968 us; speedup 1.0000x reference)
//
#include <hip/hip_runtime.h>
#include <stdint.h>
#include <stddef.h>

// MMD loss, fused: gram = X·X^T (bf16 MFMA) + 5-kernel RBF epilogue + signed mean.
// N=8192 rows (4096 src + 4096 tgt), D=256.
//
// Round-9 structure (evidence-driven deltas from R8's 60.0us):
//  R8 lesson: __launch_bounds__(256,4) + {a0,a1,b} dbuf demanded ~160 live regs
//  under a 128 cap -> SCRATCH SPILL (WRITE_SIZE 23.6MB, FETCH +6.4MB). Fix:
//  single-buffer BOTH fragment sets (a[4],b[4] = 32 VGPRs + 64 acc ~= 112 live),
//  full unroll so LLVM auto-pipelines next-chunk loads up to the cap.
//  Roofline: gram floor = L2 BW (8320 waves x 64KB = 545MB @ ~34.5TB/s ~= 16us);
//  MFMA issue is only ~2us. 16 waves/CU provide the outstanding-load concurrency.
//  Still ZERO device-scope serialization in gram (R6: fence/ticket tail cost
//  ~36ns/block device-wide).
//
// Fragment layout: elem(r,k) at (r>>4)*4096 + (k>>3)*128 + (r&15)*8 + (k&7)
// -> lane(lo,hi) fragment base byte = rowgroup*8192 + (kc*4+hi)*256 + lo*16
//    (contiguous 1KB per wave per fragment load).
//
// ws layout:
//   [0]      float  coef            (-log2(e)/(16*bandwidth))
//   [64]     double partial[2080]   -> [64, 16704)
//   [16704]  float  csp[256*256]    (per-block column-sum partials) -> 278848
//   [278848] float  sq[8192]        -> [278848, 311616)
//   [311616] ushort Xbt[8192*256]   (bf16, fragment-transposed, 4MB)

#define N_TOT 8192
#define D_DIM 256
#define BS    4096
#define NB    64      // 128-row tiles per dim
#define NTILE 2080    // upper-tri 128x128 tiles (% 8 == 0)

typedef float  f32x4  __attribute__((ext_vector_type(4)));
typedef short  bf16x8 __attribute__((ext_vector_type(8)));

__device__ __forceinline__ unsigned short f2bf(float f) {
  unsigned u = __float_as_uint(f);
  u += 0x7fffu + ((u >> 16) & 1u);   // RNE; inputs are finite
  return (unsigned short)(u >> 16);
}
__device__ __forceinline__ float bf2f(unsigned short s) {
  return __uint_as_float(((unsigned)s) << 16);
}

// ---- prep: f32 -> bf16 fragment-transposed copy + row sq-norms + column partials ----
// 256 blocks x 512 threads; 32 rows/block, 4 rows/wave.
__global__ void prep_kernel(const float* __restrict__ src, const float* __restrict__ tgt,
                            unsigned short* __restrict__ Xbt, float* __restrict__ sq,
                            float* __restrict__ csp) {
  int tid  = threadIdx.x;
  int w    = tid >> 6, lane = tid & 63;
  int blk  = blockIdx.x;
  float4 cacc = {0.f, 0.f, 0.f, 0.f};

  #pragma unroll
  for (int r = 0; r < 4; ++r) {
    int row = blk * 32 + w * 4 + r;
    const float* rowp = (row < BS) ? (src + (size_t)row * D_DIM)
                                   : (tgt + (size_t)(row - BS) * D_DIM);
    float4 v = reinterpret_cast<const float4*>(rowp)[lane];   // cols k..k+3, k=lane*4
    cacc.x += v.x; cacc.y += v.y; cacc.z += v.z; cacc.w += v.w;
    ushort4 b;
    b.x = f2bf(v.x); b.y = f2bf(v.y); b.z = f2bf(v.z); b.w = f2bf(v.w);
    int k = lane * 4;
    size_t off = ((size_t)(row >> 4)) * 4096 + (size_t)(k >> 3) * 128
               + (size_t)((row & 15) * 8) + (k & 7);
    *reinterpret_cast<ushort4*>(Xbt + off) = b;
    float fx = bf2f(b.x), fy = bf2f(b.y), fz = bf2f(b.z), fw = bf2f(b.w);
    float s = fx * fx + fy * fy + fz * fz + fw * fw;
    #pragma unroll
    for (int o = 32; o; o >>= 1) s += __shfl_down(s, o, 64);
    if (lane == 0) sq[row] = s;
  }

  __shared__ float cs[8][256];
  reinterpret_cast<float4*>(&cs[w][0])[lane] = cacc;
  __syncthreads();
  if (tid < 256) {
    float s = 0.f;
    #pragma unroll
    for (int ww = 0; ww < 8; ++ww) s += cs[ww][tid];
    csp[blk * 256 + tid] = s;   // plain store, distinct address
  }
}

// ---- bandwidth coefficient (1 block; stream order = visibility) ----
__global__ void bw_kernel(const float* __restrict__ sq, const float* __restrict__ csp,
                          float* __restrict__ coef) {
  int t = threadIdx.x, w = t >> 6, lane = t & 63;
  double s1 = 0.0;
  #pragma unroll
  for (int i = 0; i < 32; ++i) s1 += (double)sq[t + i * 256];
  double c = 0.0;
  for (int b = 0; b < 256; ++b) c += (double)csp[b * 256 + t];   // coalesced
  double s2 = c * c;
  #pragma unroll
  for (int o = 32; o; o >>= 1) { s1 += __shfl_down(s1, o, 64); s2 += __shfl_down(s2, o, 64); }
  __shared__ double rs[4], rs2[4];
  if (lane == 0) { rs[w] = s1; rs2[w] = s2; }
  __syncthreads();
  if (t == 0) {
    double S1 = rs[0] + rs[1] + rs[2] + rs[3];
    double S2 = rs2[0] + rs2[1] + rs2[2] + rs2[3];
    double S  = 2.0 * (double)N_TOT * S1 - 2.0 * S2;   // sum of all pairwise sq dists
    double bw = (S / ((double)N_TOT * (double)N_TOT - (double)N_TOT)) / 4.0;
    *coef = (float)(-1.4426950408889634 / (16.0 * bw));
  }
}

// ---- fused gram + RBF epilogue; plain-store partial per block ----
// 2080 blocks, 4 waves; each wave one 64x64 quadrant of a 128x128 tile.
__launch_bounds__(256, 4)
__global__ void gram_kernel(const unsigned short* __restrict__ Xbt, const float* __restrict__ sq,
                            const float* __restrict__ coefp, double* __restrict__ partial) {
  int tid = threadIdx.x;
  int w = tid >> 6, lane = tid & 63;
  const int lo = lane & 15, hi = lane >> 4;
  const int wr = w >> 1, wc = w & 1;

  // XCD-contiguous swizzle (2080 % 8 == 0)
  int orig = (int)blockIdx.x;
  int id   = (orig & 7) * (NTILE / 8) + (orig >> 3);

  // macro-major decode of tile -> (bi, bj), bi <= bj (macro = 8x8 tiles)
  int bi = 0, bj = 0;
  {
    int rem = id, Mi = 0, Mj = 0;
    for (Mi = 0; Mi < 8; ++Mi) {
      bool found = false;
      for (Mj = Mi; Mj < 8; ++Mj) {
        int cntm = (Mi == Mj) ? 36 : 64;
        if (rem < cntm) { found = true; break; }
        rem -= cntm;
      }
      if (found) break;
    }
    int ti, tj;
    if (Mi == Mj) {
      ti = 0;
      while (rem >= 8 - ti) { rem -= 8 - ti; ++ti; }
      tj = ti + rem;
    } else {
      ti = rem >> 3; tj = rem & 7;
    }
    bi = Mi * 8 + ti; bj = Mj * 8 + tj;
  }

  float factor = ((bi < 32) == (bj < 32)) ? 1.f : -1.f;
  if (bi != bj) factor *= 2.f;

  // fragment base (coalesced layout): rowgroup*8192 + (kc*4+hi)*256 + lo*16 bytes
  const char* pA = (const char*)Xbt + (size_t)(bi * 8 + wr * 4) * 8192 + (hi * 256 + lo * 16);
  const char* pB = (const char*)Xbt + (size_t)(bj * 8 + wc * 4) * 8192 + (hi * 256 + lo * 16);

  f32x4 acc[4][4];
  #pragma unroll
  for (int m = 0; m < 4; ++m)
    #pragma unroll
    for (int n = 0; n < 4; ++n) acc[m][n] = (f32x4){0.f, 0.f, 0.f, 0.f};

  // single-buffered fragments: min live set ~112 regs < 128 cap -> no spill;
  // full unroll lets the compiler pipeline next-chunk loads within the cap.
  #pragma unroll
  for (int kc = 0; kc < 8; ++kc) {       // D=256 -> 8 chunks of K=32
    bf16x8 a[4], b[4];
    #pragma unroll
    for (int n = 0; n < 4; ++n) b[n] = *(const bf16x8*)(pB + n * 8192 + kc * 1024);
    #pragma unroll
    for (int m = 0; m < 4; ++m) a[m] = *(const bf16x8*)(pA + m * 8192 + kc * 1024);
    #pragma unroll
    for (int m = 0; m < 4; ++m)
      #pragma unroll
      for (int n = 0; n < 4; ++n)
        acc[m][n] = __builtin_amdgcn_mfma_f32_16x16x32_bf16(a[m], b[n], acc[m][n], 0, 0, 0);
  }

  // epilogue (sq loads AFTER the K-loop to keep K-loop register pressure low)
  float coef = *coefp;
  float sqj[4], sqi[4][4];
  #pragma unroll
  for (int n = 0; n < 4; ++n) sqj[n] = sq[bj * 128 + wc * 64 + n * 16 + lo];
  #pragma unroll
  for (int m = 0; m < 4; ++m)
    #pragma unroll
    for (int r = 0; r < 4; ++r) sqi[m][r] = sq[bi * 128 + wr * 64 + m * 16 + hi * 4 + r];

  float psum = 0.f;
  #pragma unroll
  for (int m = 0; m < 4; ++m) {
    #pragma unroll
    for (int n = 0; n < 4; ++n) {
      #pragma unroll
      for (int r = 0; r < 4; ++r) {
        float g  = acc[m][n][r];
        float d2 = fmaxf(fmaf(-2.f, g, sqi[m][r] + sqj[n]), 0.f);
        float u  = __builtin_amdgcn_exp2f(d2 * coef);
        float u2 = u * u, u4 = u2 * u2, u8 = u4 * u4, u16 = u8 * u8;
        psum += (u + u2) + (u4 + u8) + u16;
      }
    }
  }
  #pragma unroll
  for (int o = 32; o; o >>= 1) psum += __shfl_down(psum, o, 64);
  __shared__ float wred[4];
  if (lane == 0) wred[w] = psum;
  __syncthreads();
  if (tid == 0)
    partial[id] = (double)((wred[0] + wred[1] + wred[2] + wred[3]) * factor);  // plain store
}

// ---- final reduction (1 block; stream order = visibility) ----
__global__ void reduce_kernel(const double* __restrict__ partial, float* __restrict__ out) {
  int t = threadIdx.x, w = t >> 6, lane = t & 63;
  double s = 0.0;
  for (int i = t; i < NTILE; i += 256) s += partial[i];
  #pragma unroll
  for (int o = 32; o; o >>= 1) s += __shfl_down(s, o, 64);
  __shared__ double rs[4];
  if (lane == 0) rs[w] = s;
  __syncthreads();
  if (t == 0)
    out[0] = (float)((rs[0] + rs[1] + rs[2] + rs[3]) / ((double)BS * (double)BS));
}

extern "C" void kernel_launch(void* const* d_in, const int* in_sizes, int n_in,
                              void* d_out, int out_size, void* d_ws, size_t ws_size,
                              hipStream_t stream) {
  const float* src = (const float*)d_in[0];
  const float* tgt = (const float*)d_in[1];
  char* ws = (char*)d_ws;
  float*  coef    = (float*)(ws + 0);
  double* partial = (double*)(ws + 64);
  float*  csp     = (float*)(ws + 16704);
  float*  sq      = (float*)(ws + 278848);
  unsigned short* Xbt = (unsigned short*)(ws + 311616);
  float* out = (float*)d_out;

  prep_kernel<<<256, 512, 0, stream>>>(src, tgt, Xbt, sq, csp);
  bw_kernel<<<1, 256, 0, stream>>>(sq, csp, coef);
  gram_kernel<<<NTILE, 256, 0, stream>>>(Xbt, sq, coef, partial);
  reduce_kernel<<<1, 256, 0, stream>>>(partial, out);
}

// Round 10
// 58.766 us; speedup vs baseline: 1.0715x; 1.0715x over previous
//
#include <hip/hip_runtime.h>
#include <stdint.h>
#include <stddef.h>

// MMD loss, fused: gram = X·X^T (bf16 MFMA) + 5-kernel RBF epilogue + signed mean.
// N=8192 rows (4096 src + 4096 tgt), D=256.
//
// Round-10 structure (evidence-driven deltas from R9's 63us):
//  R8/R9 lesson: under __launch_bounds__(256,4) the compiler auto-pipelines the
//  unrolled K-loop past the 128-reg cap -> scratch spill (WRITE 23-38MB); and
//  duration ~42-45us was INVARIANT to spill magnitude, coalescing, locality,
//  serialization -> remaining suspects: 2x panel-read redundancy + per-iter
//  full-batch vmcnt stalls at ~2 waves/SIMD.
//  NEW: A panel staged in LDS ONCE per block (single barrier, NOT the R2
//  per-K-step-barrier structure): Xbt fragment layout makes the A panel a
//  contiguous 64KB identity copy -> 64 x global_load_lds(width16). K-loop
//  reads A via ds_read_b128 (contiguous 1KB/wave, conflict-free) + B direct
//  from L2. Traffic 256->192KB/block. LDS 64KB caps occupancy at 2 blocks/CU,
//  so (256,2) frees ~256 regs for deep B-prefetch with ZERO spill.
//
// Fragment layout: elem(r,k) at (r>>4)*4096 + (k>>3)*128 + (r&15)*8 + (k&7)
// -> lane(lo,hi) fragment base byte = rowgroup*8192 + (kc*4+hi)*256 + lo*16
//    (contiguous 1KB per wave per fragment; panel = 8 rowgroups = 64KB contig).
//
// ws layout:
//   [0]      float  coef            (-log2(e)/(16*bandwidth))
//   [64]     double partial[2080]   -> [64, 16704)
//   [16704]  float  csp[256*256]    (per-block column-sum partials) -> 278848
//   [278848] float  sq[8192]        -> [278848, 311616)
//   [311616] ushort Xbt[8192*256]   (bf16, fragment-transposed, 4MB)

#define N_TOT 8192
#define D_DIM 256
#define BS    4096
#define NB    64      // 128-row tiles per dim
#define NTILE 2080    // upper-tri 128x128 tiles (% 8 == 0)

typedef float  f32x4  __attribute__((ext_vector_type(4)));
typedef short  bf16x8 __attribute__((ext_vector_type(8)));

typedef __attribute__((address_space(1))) const unsigned int gas_u32;
typedef __attribute__((address_space(3))) unsigned int       lds_u32;

__device__ __forceinline__ unsigned short f2bf(float f) {
  unsigned u = __float_as_uint(f);
  u += 0x7fffu + ((u >> 16) & 1u);   // RNE; inputs are finite
  return (unsigned short)(u >> 16);
}
__device__ __forceinline__ float bf2f(unsigned short s) {
  return __uint_as_float(((unsigned)s) << 16);
}

// ---- prep: f32 -> bf16 fragment-transposed copy + row sq-norms + column partials ----
// 256 blocks x 512 threads; 32 rows/block, 4 rows/wave.
__global__ void prep_kernel(const float* __restrict__ src, const float* __restrict__ tgt,
                            unsigned short* __restrict__ Xbt, float* __restrict__ sq,
                            float* __restrict__ csp) {
  int tid  = threadIdx.x;
  int w    = tid >> 6, lane = tid & 63;
  int blk  = blockIdx.x;
  float4 cacc = {0.f, 0.f, 0.f, 0.f};

  #pragma unroll
  for (int r = 0; r < 4; ++r) {
    int row = blk * 32 + w * 4 + r;
    const float* rowp = (row < BS) ? (src + (size_t)row * D_DIM)
                                   : (tgt + (size_t)(row - BS) * D_DIM);
    float4 v = reinterpret_cast<const float4*>(rowp)[lane];   // cols k..k+3, k=lane*4
    cacc.x += v.x; cacc.y += v.y; cacc.z += v.z; cacc.w += v.w;
    ushort4 b;
    b.x = f2bf(v.x); b.y = f2bf(v.y); b.z = f2bf(v.z); b.w = f2bf(v.w);
    int k = lane * 4;
    size_t off = ((size_t)(row >> 4)) * 4096 + (size_t)(k >> 3) * 128
               + (size_t)((row & 15) * 8) + (k & 7);
    *reinterpret_cast<ushort4*>(Xbt + off) = b;
    float fx = bf2f(b.x), fy = bf2f(b.y), fz = bf2f(b.z), fw = bf2f(b.w);
    float s = fx * fx + fy * fy + fz * fz + fw * fw;
    #pragma unroll
    for (int o = 32; o; o >>= 1) s += __shfl_down(s, o, 64);
    if (lane == 0) sq[row] = s;
  }

  __shared__ float cs[8][256];
  reinterpret_cast<float4*>(&cs[w][0])[lane] = cacc;
  __syncthreads();
  if (tid < 256) {
    float s = 0.f;
    #pragma unroll
    for (int ww = 0; ww < 8; ++ww) s += cs[ww][tid];
    csp[blk * 256 + tid] = s;   // plain store, distinct address
  }
}

// ---- bandwidth coefficient (1 block; stream order = visibility) ----
__global__ void bw_kernel(const float* __restrict__ sq, const float* __restrict__ csp,
                          float* __restrict__ coef) {
  int t = threadIdx.x, w = t >> 6, lane = t & 63;
  double s1 = 0.0;
  #pragma unroll
  for (int i = 0; i < 32; ++i) s1 += (double)sq[t + i * 256];
  double c = 0.0;
  #pragma unroll 16
  for (int b = 0; b < 256; ++b) c += (double)csp[b * 256 + t];   // coalesced
  double s2 = c * c;
  #pragma unroll
  for (int o = 32; o; o >>= 1) { s1 += __shfl_down(s1, o, 64); s2 += __shfl_down(s2, o, 64); }
  __shared__ double rs[4], rs2[4];
  if (lane == 0) { rs[w] = s1; rs2[w] = s2; }
  __syncthreads();
  if (t == 0) {
    double S1 = rs[0] + rs[1] + rs[2] + rs[3];
    double S2 = rs2[0] + rs2[1] + rs2[2] + rs2[3];
    double S  = 2.0 * (double)N_TOT * S1 - 2.0 * S2;   // sum of all pairwise sq dists
    double bw = (S / ((double)N_TOT * (double)N_TOT - (double)N_TOT)) / 4.0;
    *coef = (float)(-1.4426950408889634 / (16.0 * bw));
  }
}

// ---- fused gram + RBF epilogue; A-panel in LDS (single barrier), B direct ----
// 2080 blocks, 4 waves; each wave one 64x64 quadrant of a 128x128 tile.
__launch_bounds__(256, 2)
__global__ void gram_kernel(const unsigned short* __restrict__ Xbt, const float* __restrict__ sq,
                            const float* __restrict__ coefp, double* __restrict__ partial) {
  __shared__ __align__(16) unsigned char Alds[65536];   // full 128x256 A panel

  int tid = threadIdx.x;
  int w = tid >> 6, lane = tid & 63;
  const int lo = lane & 15, hi = lane >> 4;
  const int wr = w >> 1, wc = w & 1;

  // XCD-contiguous swizzle (2080 % 8 == 0)
  int orig = (int)blockIdx.x;
  int id   = (orig & 7) * (NTILE / 8) + (orig >> 3);

  // macro-major decode of tile -> (bi, bj), bi <= bj (macro = 8x8 tiles)
  int bi = 0, bj = 0;
  {
    int rem = id, Mi = 0, Mj = 0;
    for (Mi = 0; Mi < 8; ++Mi) {
      bool found = false;
      for (Mj = Mi; Mj < 8; ++Mj) {
        int cntm = (Mi == Mj) ? 36 : 64;
        if (rem < cntm) { found = true; break; }
        rem -= cntm;
      }
      if (found) break;
    }
    int ti, tj;
    if (Mi == Mj) {
      ti = 0;
      while (rem >= 8 - ti) { rem -= 8 - ti; ++ti; }
      tj = ti + rem;
    } else {
      ti = rem >> 3; tj = rem & 7;
    }
    bi = Mi * 8 + ti; bj = Mj * 8 + tj;
  }

  float factor = ((bi < 32) == (bj < 32)) ? 1.f : -1.f;
  if (bi != bj) factor *= 2.f;

  const char* Xb = (const char*)Xbt;

  // stage A panel (64KB, identity copy: fragment layout is panel-contiguous).
  // wave w stages bytes [w*16384, (w+1)*16384): 16 x global_load_lds width-16.
  {
    const char* srcA = Xb + (size_t)bi * 65536 + w * 16384 + lane * 16;
    unsigned char* dstA = Alds + w * 16384;
    #pragma unroll
    for (int i = 0; i < 16; ++i)
      __builtin_amdgcn_global_load_lds((gas_u32*)(srcA + i * 1024),
                                       (lds_u32*)(dstA + i * 1024), 16, 0, 0);
  }

  // B fragment base, direct from global/L2
  const char* pB = Xb + (size_t)(bj * 8 + wc * 4) * 8192 + (hi * 256 + lo * 16);
  const char* pAl = (const char*)Alds + (size_t)(wr * 4) * 8192 + (hi * 256 + lo * 16);

  f32x4 acc[4][4];
  #pragma unroll
  for (int m = 0; m < 4; ++m)
    #pragma unroll
    for (int n = 0; n < 4; ++n) acc[m][n] = (f32x4){0.f, 0.f, 0.f, 0.f};

  __syncthreads();   // drains the staging loads (compiler emits vmcnt(0))

  #pragma unroll
  for (int kc = 0; kc < 8; ++kc) {       // D=256 -> 8 chunks of K=32
    bf16x8 a[4], b[4];
    #pragma unroll
    for (int n = 0; n < 4; ++n) b[n] = *(const bf16x8*)(pB + n * 8192 + kc * 1024);
    #pragma unroll
    for (int m = 0; m < 4; ++m) a[m] = *(const bf16x8*)(pAl + m * 8192 + kc * 1024);
    #pragma unroll
    for (int m = 0; m < 4; ++m)
      #pragma unroll
      for (int n = 0; n < 4; ++n)
        acc[m][n] = __builtin_amdgcn_mfma_f32_16x16x32_bf16(a[m], b[n], acc[m][n], 0, 0, 0);
  }

  // epilogue: d2 = max(sq_i + sq_j - 2g, 0); kernels = u+u^2+u^4+u^8+u^16, u=exp2(d2*coef)
  float coef = *coefp;
  float sqj[4], sqi[4][4];
  #pragma unroll
  for (int n = 0; n < 4; ++n) sqj[n] = sq[bj * 128 + wc * 64 + n * 16 + lo];
  #pragma unroll
  for (int m = 0; m < 4; ++m)
    #pragma unroll
    for (int r = 0; r < 4; ++r) sqi[m][r] = sq[bi * 128 + wr * 64 + m * 16 + hi * 4 + r];

  float psum = 0.f;
  #pragma unroll
  for (int m = 0; m < 4; ++m) {
    #pragma unroll
    for (int n = 0; n < 4; ++n) {
      #pragma unroll
      for (int r = 0; r < 4; ++r) {
        float g  = acc[m][n][r];
        float d2 = fmaxf(fmaf(-2.f, g, sqi[m][r] + sqj[n]), 0.f);
        float u  = __builtin_amdgcn_exp2f(d2 * coef);
        float u2 = u * u, u4 = u2 * u2, u8 = u4 * u4, u16 = u8 * u8;
        psum += (u + u2) + (u4 + u8) + u16;
      }
    }
  }
  #pragma unroll
  for (int o = 32; o; o >>= 1) psum += __shfl_down(psum, o, 64);
  __shared__ float wred[4];
  if (lane == 0) wred[w] = psum;
  __syncthreads();
  if (tid == 0)
    partial[id] = (double)((wred[0] + wred[1] + wred[2] + wred[3]) * factor);  // plain store
}

// ---- final reduction (1 block; stream order = visibility) ----
__global__ void reduce_kernel(const double* __restrict__ partial, float* __restrict__ out) {
  int t = threadIdx.x, w = t >> 6, lane = t & 63;
  double s = 0.0;
  for (int i = t; i < NTILE; i += 256) s += partial[i];
  #pragma unroll
  for (int o = 32; o; o >>= 1) s += __shfl_down(s, o, 64);
  __shared__ double rs[4];
  if (lane == 0) rs[w] = s;
  __syncthreads();
  if (t == 0)
    out[0] = (float)((rs[0] + rs[1] + rs[2] + rs[3]) / ((double)BS * (double)BS));
}

extern "C" void kernel_launch(void* const* d_in, const int* in_sizes, int n_in,
                              void* d_out, int out_size, void* d_ws, size_t ws_size,
                              hipStream_t stream) {
  const float* src = (const float*)d_in[0];
  const float* tgt = (const float*)d_in[1];
  char* ws = (char*)d_ws;
  float*  coef    = (float*)(ws + 0);
  double* partial = (double*)(ws + 64);
  float*  csp     = (float*)(ws + 16704);
  float*  sq      = (float*)(ws + 278848);
  unsigned short* Xbt = (unsigned short*)(ws + 311616);
  float* out = (float*)d_out;

  prep_kernel<<<256, 512, 0, stream>>>(src, tgt, Xbt, sq, csp);
  bw_kernel<<<1, 256, 0, stream>>>(sq, csp, coef);
  gram_kernel<<<NTILE, 256, 0, stream>>>(Xbt, sq, coef, partial);
  reduce_kernel<<<1, 256, 0, stream>>>(partial, out);
}